// Round 7
// baseline (265.154 us; speedup 1.0000x reference)
//
#include <hip/hip_runtime.h>

#define T_DIM 2048
#define D_DIM 1024
#define H_DIM 1024
#define B_DIM 4

typedef __attribute__((ext_vector_type(8))) __bf16 bf16x8;
typedef __attribute__((ext_vector_type(4))) float f32x4;

__device__ __forceinline__ unsigned short f2b(float f) {
  union { float f; unsigned int u; } x; x.f = f;
  unsigned int r = x.u + 0x7fffu + ((x.u >> 16) & 1u);
  return (unsigned short)(r >> 16);
}
__device__ __forceinline__ float b2f(unsigned short b) {
  union { unsigned int u; float f; } x; x.u = ((unsigned int)b) << 16;
  return x.f;
}

__device__ __forceinline__ void async16(unsigned short* l, const unsigned short* g) {
  __builtin_amdgcn_global_load_lds((const __attribute__((address_space(1))) void*)g,
                                   (__attribute__((address_space(3))) void*)l,
                                   16, 0, 0);
}

// ---------------- fused weights prep: 4x f32->bf16 cvt + bias concat ----------------
__global__ __launch_bounds__(256) void prep_kernel(const float* __restrict__ ew,
                                                   const float* __restrict__ kw,
                                                   const float* __restrict__ qw,
                                                   const float* __restrict__ vw,
                                                   const float* __restrict__ kb,
                                                   const float* __restrict__ qb,
                                                   const float* __restrict__ vb,
                                                   unsigned short* __restrict__ oe,
                                                   unsigned short* __restrict__ okqv,
                                                   float* __restrict__ ob) {
  int bid = blockIdx.x;
  if (bid == 4096) {               // bias concat: 3072 floats = 768 float4
    #pragma unroll
    for (int k = 0; k < 3; k++) {
      int f4 = threadIdx.x + k * 256;
      int fi = f4 * 4;
      const float* src = fi < 1024 ? kb + fi : (fi < 2048 ? qb + (fi - 1024) : vb + (fi - 2048));
      *(float4*)(&ob[fi]) = *(const float4*)src;
    }
    return;
  }
  int i = bid * 256 + threadIdx.x;   // float4 index over 4 x 256K
  int seg = i >> 18;
  int off = i & 262143;
  const float* in = seg == 0 ? ew : (seg == 1 ? kw : (seg == 2 ? qw : vw));
  unsigned short* out = seg == 0 ? oe : okqv + (size_t)(seg - 1) * 1048576;
  float4 v = ((const float4*)in)[off];
  ushort4 o;
  o.x = f2b(v.x); o.y = f2b(v.y); o.z = f2b(v.z); o.w = f2b(v.w);
  ((ushort4*)out)[off] = o;
}

// ---------------- tiled transpose (+cvt to bf16) ----------------
template <typename TIN>
__global__ __launch_bounds__(256) void transpose_kernel(const TIN* __restrict__ in,
                                                        unsigned short* __restrict__ out,
                                                        int inLD, size_t sIn, int R, size_t sOut) {
  __shared__ TIN tile[32][33];
  int c0 = blockIdx.x * 32, r0 = blockIdx.y * 32;
  int tx = threadIdx.x & 31, ty = threadIdx.x >> 5;
  const TIN* I = in + (size_t)blockIdx.z * sIn;
  #pragma unroll
  for (int i = 0; i < 32; i += 8)
    tile[ty + i][tx] = I[(size_t)(r0 + ty + i) * inLD + (c0 + tx)];
  __syncthreads();
  unsigned short* O = out + (size_t)blockIdx.z * sOut;
  #pragma unroll
  for (int i = 0; i < 32; i += 8) {
    TIN v = tile[tx][ty + i];
    unsigned short bb;
    if constexpr (sizeof(TIN) == 4) bb = f2b((float)v);
    else bb = (unsigned short)v;
    O[(size_t)(c0 + ty + i) * R + (r0 + tx)] = bb;
  }
}

// ============ 256x256 8-phase B^T GEMM: C[i,j] = sum_k A[i,k]*B[j,k] (+bias[j]) ============
// 512 thr = 8 waves (2M x 4N), per-wave 128x64 (acc[8][4]), BK=64, 2 K-tiles/iter, 8 phases.
// LDS: 2 dbuf x (A 256x64 + B 256x64) bf16 = 128 KiB, XOR-swizzled (chunk ^= row&7).
// LIVENESS-SAFE deep ledger (R6's bug: staged into a buffer before its reads finished).
// Region last-reads per iter: buf0-B@P2, buf0-A@P3, buf1-B@P6, buf1-A@P7. Stages are placed
// at the earliest barrier-separated slot AFTER the region's last read:
//   P3: B(ta+2)h0 | P4: A(ta+2)h0, B(ta+2)h1 | P5: A(ta+2)h1 | P7: B(tb+2)h0
//   P8: A(tb+2)h0, B(tb+2)h1, A(tb+2)h1
// FIFO vmcnt (2 loads per half-stage): entering iter: 8 outstanding (= tile tb, staged
// prev P7/P8). P4: 14 outstanding -> vmcnt(6) retires tile tb (4-5 phases slack).
// P8: 16 outstanding -> vmcnt(8) retires tile ta+2 (3-5 phases slack). All slack >= ~900cy.
// Uniform iterations; final iter stages nothing, vmcnt(0) at P4.
// Prologue: tiles 0,1 (16 halves... 16 loads); vmcnt(8) -> tile0 resident.
// OMODE: 1 bf16 C (+bias); 2 f32 C; 4 PV-fused out[b][d][t] = acc + m_res (transposed).
// SKIP: 1 causal block skip (logits [s][t]: bn<bm); 2 causal K-limit (PV: nt=(bm+1)*4).

#define BAR_  asm volatile("s_barrier" ::: "memory")
#define VM8_  asm volatile("s_waitcnt vmcnt(8)" ::: "memory")
#define VM6_  asm volatile("s_waitcnt vmcnt(6)" ::: "memory")
#define VM0_  asm volatile("s_waitcnt vmcnt(0)" ::: "memory")

// stage half h (rows h*128..h*128+127) of A/B K-tile t into buf (t&1): 2 async16/thread
#define STGAH(t, h) do { \
    unsigned short* d_ = ldsA + ((t) & 1) * 16384 + (h) * 8192 + tid * 8;            \
    const unsigned short* s_ = A + (size_t)((h) * 128 + rl0) * lda + (t) * 64 + ce;  \
    async16(d_, s_); async16(d_ + 4096, s_ + (size_t)64 * lda); } while (0)
#define STGBH(t, h) do { \
    unsigned short* d_ = ldsB + ((t) & 1) * 16384 + (h) * 8192 + tid * 8;            \
    const unsigned short* s_ = Bm + (size_t)((h) * 128 + rl0) * ldb + (t) * 64 + ce; \
    async16(d_, s_); async16(d_ + 4096, s_ + (size_t)64 * ldb); } while (0)

#define FRG(base, row, ks) \
  (*(const bf16x8*)((base) + (row) * 64 + ((((ks) << 2) | hi) ^ (lo & 7)) * 8))

#define LDA_(bA, mb)                                                   \
  _Pragma("unroll") for (int m_ = 0; m_ < 4; m_++) {                   \
    int row_ = wr * 128 + ((mb) + m_) * 16 + lo;                       \
    af[m_][0] = FRG(bA, row_, 0);                                      \
    af[m_][1] = FRG(bA, row_, 1);                                      \
  }

#define LDB_(bB, nb, bg)                                               \
  _Pragma("unroll") for (int n_ = 0; n_ < 2; n_++) {                   \
    int row_ = wc * 64 + ((nb) + n_) * 16 + lo;                        \
    bg[n_][0] = FRG(bB, row_, 0);                                      \
    bg[n_][1] = FRG(bB, row_, 1);                                      \
  }

#define MM_(mb, nb, bg)                                                              \
  __builtin_amdgcn_s_setprio(1);                                                     \
  _Pragma("unroll") for (int m_ = 0; m_ < 4; m_++)                                   \
    _Pragma("unroll") for (int n_ = 0; n_ < 2; n_++) {                               \
      acc[(mb) + m_][(nb) + n_] = __builtin_amdgcn_mfma_f32_16x16x32_bf16(           \
          af[m_][0], bg[n_][0], acc[(mb) + m_][(nb) + n_], 0, 0, 0);                 \
      acc[(mb) + m_][(nb) + n_] = __builtin_amdgcn_mfma_f32_16x16x32_bf16(           \
          af[m_][1], bg[n_][1], acc[(mb) + m_][(nb) + n_], 0, 0, 0);                 \
    }                                                                                \
  __builtin_amdgcn_s_setprio(0);

template <int OMODE, bool BIAS, int SKIP>
__global__ __launch_bounds__(512, 2)
void gemm8_kernel(const unsigned short* __restrict__ A,
                  const unsigned short* __restrict__ Bm,
                  const float* __restrict__ bias,
                  float* __restrict__ Cf, unsigned short* __restrict__ Cb,
                  const unsigned short* __restrict__ mres,
                  int N, int K, int lda, int ldb,
                  size_t sAb, size_t sBb, size_t sCb) {
  __shared__ __align__(16) unsigned short smem[65536];   // 128 KiB
  unsigned short* ldsA = smem;            // 2 x 256x64
  unsigned short* ldsB = smem + 32768;    // 2 x 256x64

  // XCD-aware bijective swizzle (nwg % 8 == 0 for all our grids)
  int gx = gridDim.x;
  int nwg = gx * gridDim.y;
  int flat = blockIdx.x + gx * blockIdx.y;
  int cpx = nwg >> 3;
  int f2 = (flat & 7) * cpx + (flat >> 3);
  int bn = f2 % gx, bm = f2 / gx;
  int bz = blockIdx.z;
  if (SKIP == 1 && bn < bm) return;       // block's max t < min s -> all masked

  A  += (size_t)bz * sAb + (size_t)bm * 256 * lda;
  Bm += (size_t)bz * sBb + (size_t)bn * 256 * ldb;

  int tid = threadIdx.x;
  int lane = tid & 63, wid = tid >> 6;
  int wr = wid >> 2, wc = wid & 3;
  int lo = lane & 15, hi = lane >> 4;
  int rl0 = tid >> 3;
  int ce = 8 * ((tid & 7) ^ (rl0 & 7));   // pre-swizzled source chunk

  int nt = K / 64;
  if (SKIP == 2) nt = (bm + 1) * 4;       // PV: s < (bm+1)*256

  bf16x8 af[4][2], bg0[2][2], bg1[2][2];
  f32x4 acc[8][4] = {};

  // prologue: tiles 0 and 1 fully staged; vmcnt(8) -> tile0 resident, tile1 in flight
  STGAH(0, 0); STGAH(0, 1); STGBH(0, 0); STGBH(0, 1);
  STGAH(1, 0); STGAH(1, 1); STGBH(1, 0); STGBH(1, 1);
  VM8_; BAR_;

  const unsigned short* bA0 = ldsA;            // ta even -> buf0
  const unsigned short* bB0 = ldsB;
  const unsigned short* bA1 = ldsA + 16384;    // tb odd -> buf1
  const unsigned short* bB1 = ldsB + 16384;

  int nIter = nt >> 1;
  for (int i = 0; i < nIter; i++) {
    bool last = (i == nIter - 1);
    int ta = 2 * i, tb = ta + 1;
    // P1
    LDA_(bA0, 0) LDB_(bB0, 0, bg0)
    BAR_; MM_(0, 0, bg0) BAR_;
    // P2
    LDB_(bB0, 2, bg1)
    BAR_; MM_(0, 2, bg1) BAR_;
    // P3  (buf0-B reads done @P2 -> may stage B(ta+2)h0)
    LDA_(bA0, 4)
    if (!last) STGBH(ta + 2, 0);
    BAR_; MM_(4, 0, bg0) BAR_;
    // P4  (buf0-A reads done @P3)
    if (!last) { STGAH(ta + 2, 0); STGBH(ta + 2, 1); }
    BAR_; MM_(4, 2, bg1)
    if (last) { VM0_; } else { VM6_; }   // retire tile tb (staged prev P7/P8)
    BAR_;
    // P5
    LDA_(bA1, 0) LDB_(bB1, 0, bg0)
    if (!last) STGAH(ta + 2, 1);
    BAR_; MM_(0, 0, bg0) BAR_;
    // P6
    LDB_(bB1, 2, bg1)
    BAR_; MM_(0, 2, bg1) BAR_;
    // P7  (buf1-B reads done @P6)
    LDA_(bA1, 4)
    if (!last) STGBH(tb + 2, 0);
    BAR_; MM_(4, 0, bg0) BAR_;
    // P8  (buf1-A reads done @P7)
    if (!last) { STGAH(tb + 2, 0); STGBH(tb + 2, 1); STGAH(tb + 2, 1); }
    BAR_; MM_(4, 2, bg1)
    if (!last) VM8_;                     // retire tile ta+2 (staged P3..P5)
    BAR_;
  }

  // ---------------- epilogue: LDS retile -> coalesced 16B stores ----------------
  __syncthreads();
  int row0 = bm * 256, col0 = bn * 256;
  size_t coff = (size_t)bz * sCb;

  if (OMODE == 1) {
    unsigned short* ep = smem;   // [128][264] padded, 2 halves of 128 rows
    #pragma unroll
    for (int half = 0; half < 2; half++) {
      __syncthreads();
      if (wr == half) {
        #pragma unroll
        for (int n = 0; n < 4; n++) {
          int cl = wc * 64 + n * 16 + lo;
          float bv = BIAS ? bias[col0 + cl] : 0.f;
          #pragma unroll
          for (int m = 0; m < 8; m++) {
            int rl = m * 16 + hi * 4;
            #pragma unroll
            for (int j = 0; j < 4; j++)
              ep[(rl + j) * 264 + cl] = f2b(acc[m][n][j] + bv);
          }
        }
      }
      __syncthreads();
      #pragma unroll
      for (int it = 0; it < 8; it++) {
        int idx = it * 512 + tid, r = idx >> 5, c = idx & 31;
        *(uint4*)(Cb + coff + (size_t)(row0 + half * 128 + r) * N + col0 + c * 8) =
            *(const uint4*)(ep + r * 264 + c * 8);
      }
    }
  } else if (OMODE == 2) {
    float* ep = (float*)smem;    // [64][260] padded, 4 quarters of 64 rows
    #pragma unroll
    for (int q = 0; q < 4; q++) {
      __syncthreads();
      if (wr == (q >> 1)) {
        int mb = (q & 1) * 4;
        #pragma unroll
        for (int n = 0; n < 4; n++) {
          int cl = wc * 64 + n * 16 + lo;
          #pragma unroll
          for (int mm = 0; mm < 4; mm++) {
            int rl = mm * 16 + hi * 4;
            #pragma unroll
            for (int j = 0; j < 4; j++) ep[(rl + j) * 260 + cl] = acc[mb + mm][n][j];
          }
        }
      }
      __syncthreads();
      #pragma unroll
      for (int it = 0; it < 8; it++) {
        int idx = it * 512 + tid, r = idx >> 6, c = idx & 63;
        *(float4*)(Cf + coff + (size_t)(row0 + q * 64 + r) * N + col0 + c * 4) =
            *(const float4*)(ep + r * 260 + c * 4);
      }
    }
  } else {   // OMODE == 4: out[b][d][t] = acc + m[b][t][d]; quarters = wc (64 d each)
    float* ep = (float*)smem;    // [64 d][260 t] padded
    #pragma unroll
    for (int q = 0; q < 4; q++) {
      __syncthreads();
      if (wc == q) {
        #pragma unroll
        for (int n = 0; n < 4; n++) {
          int dl = n * 16 + lo;
          #pragma unroll
          for (int m = 0; m < 8; m++) {
            int rl = wr * 128 + m * 16 + hi * 4;
            #pragma unroll
            for (int j = 0; j < 4; j++) {
              float v = acc[m][n][j] +
                  b2f(mres[((size_t)bz * T_DIM + row0 + rl + j) * D_DIM + col0 + q * 64 + dl]);
              ep[dl * 260 + rl + j] = v;
            }
          }
        }
      }
      __syncthreads();
      #pragma unroll
      for (int it = 0; it < 8; it++) {
        int idx = it * 512 + tid, r = idx >> 6, c = idx & 63;
        *(float4*)(Cf + ((size_t)bz * D_DIM + col0 + q * 64 + r) * T_DIM + row0 + c * 4) =
            *(const float4*)(ep + r * 260 + c * 4);
      }
    }
  }
}

// ---------------- softmax stats over rows of logitsT (= axis-1 of logits) ----------------
__device__ __forceinline__ float wred_max(float v) {
  #pragma unroll
  for (int o = 32; o > 0; o >>= 1) v = fmaxf(v, __shfl_down(v, o, 64));
  return v;
}
__device__ __forceinline__ float wred_sum(float v) {
  #pragma unroll
  for (int o = 32; o > 0; o >>= 1) v += __shfl_down(v, o, 64);
  return v;
}

__global__ __launch_bounds__(256) void softmax_stats_kernel(const float* __restrict__ lg,
                                                            float* __restrict__ smax,
                                                            float* __restrict__ sinv) {
  __shared__ float sb[4];
  int row = blockIdx.x;            // b*T + s
  int s = row & (T_DIM - 1);
  int t0 = (s >> 8) << 8;          // causal: logits computed for t >= 256-aligned floor
  const float* Lr = lg + (size_t)row * T_DIM;
  float mx = -3.4e38f;
  for (int t = t0 + threadIdx.x; t < T_DIM; t += 256)
    if (t >= s) mx = fmaxf(mx, Lr[t]);
  mx = wred_max(mx);
  if ((threadIdx.x & 63) == 0) sb[threadIdx.x >> 6] = mx;
  __syncthreads();
  mx = fmaxf(fmaxf(sb[0], sb[1]), fmaxf(sb[2], sb[3]));
  __syncthreads();
  float sum = 0.f;
  for (int t = t0 + threadIdx.x; t < T_DIM; t += 256)
    if (t >= s) sum += __expf(Lr[t] - mx);
  sum = wred_sum(sum);
  if ((threadIdx.x & 63) == 0) sb[threadIdx.x >> 6] = sum;
  __syncthreads();
  if (threadIdx.x == 0) {
    float tot = sb[0] + sb[1] + sb[2] + sb[3];
    smax[row] = mx;
    sinv[row] = 1.0f / (tot * 32.0f);   // fold 1/sqrt(D)=1/32 into the normalizer
  }
}

// ---------------- normalize + transpose: probs[t][s] bf16 from logitsT[s][t] ----------------
__global__ __launch_bounds__(256) void probs_kernel(const float* __restrict__ lg,
                                                    const float* __restrict__ smax,
                                                    const float* __restrict__ sinv,
                                                    unsigned short* __restrict__ probs) {
  int bz = blockIdx.z;
  int t0 = blockIdx.x * 32, s0 = blockIdx.y * 32;
  if (s0 >= (((t0 >> 8) + 1) << 8)) return;   // never read by the K-limited PV GEMM (256-tiles)
  __shared__ float tile[32][33];
  int tx = threadIdx.x & 31, ty = threadIdx.x >> 5;
  const float* L = lg + (size_t)bz * T_DIM * T_DIM;
  #pragma unroll
  for (int i = 0; i < 32; i += 8)
    tile[ty + i][tx] = L[(size_t)(s0 + ty + i) * T_DIM + (t0 + tx)];
  __syncthreads();
  unsigned short* P = probs + (size_t)bz * T_DIM * T_DIM;
  #pragma unroll
  for (int i = 0; i < 32; i += 8) {
    int t = t0 + ty + i, s = s0 + tx;
    float x = tile[tx][ty + i];
    float p = (t >= s) ? __expf(x - smax[bz * T_DIM + s]) * sinv[bz * T_DIM + s] : 0.f;
    P[(size_t)t * T_DIM + s] = f2b(p);
  }
}

extern "C" void kernel_launch(void* const* d_in, const int* in_sizes, int n_in,
                              void* d_out, int out_size, void* d_ws, size_t ws_size,
                              hipStream_t stream) {
  const float* minibatch = (const float*)d_in[0];
  const float* emb_w   = (const float*)d_in[1];
  const float* emb_b   = (const float*)d_in[2];
  const float* key_w   = (const float*)d_in[3];
  const float* key_b   = (const float*)d_in[4];
  const float* query_w = (const float*)d_in[5];
  const float* query_b = (const float*)d_in[6];
  const float* value_w = (const float*)d_in[7];
  const float* value_b = (const float*)d_in[8];
  float* out = (float*)d_out;

  char* ws = (char*)d_ws;
  const size_t MB = 1ull << 20;
  unsigned short* wbf_emb = (unsigned short*)(ws + 0 * MB);    // 2 MB
  unsigned short* wbf_kqv = (unsigned short*)(ws + 2 * MB);    // 6 MB [key|query|value]
  float*          kqv_b   = (float*)(ws + 8 * MB);             // 12 KB
  unsigned short* m_bf    = (unsigned short*)(ws + 9 * MB);    // 16 MB, live to end
  unsigned short* KQV     = (unsigned short*)(ws + 25 * MB);   // 48 MB (dead after logits)
  unsigned short* VT_bf   = (unsigned short*)(ws + 73 * MB);   // 16 MB
  float*          logitsT = (float*)(ws + 89 * MB);            // 64 MB
  unsigned short* xT      = (unsigned short*)(ws + 153 * MB);  // 16 MB (dead after emb GEMM)
  unsigned short* probs   = (unsigned short*)(ws + 153 * MB);  // 32 MB, aliases xT
  float*          smax    = (float*)(ws + 186 * MB);
  float*          sinv    = (float*)(ws + 186 * MB + 32768);

  const int BT = B_DIM * T_DIM;   // 8192
  const size_t TT = (size_t)T_DIM * T_DIM;

  // 1) weights -> bf16 + bias concat (single launch)
  prep_kernel<<<4097, 256, 0, stream>>>(emb_w, key_w, query_w, value_w,
                                        key_b, query_b, value_b,
                                        wbf_emb, wbf_kqv, kqv_b);

  // 2) xT[b][t][h] = minibatch[b][h][t], bf16
  transpose_kernel<float><<<dim3(T_DIM / 32, H_DIM / 32, B_DIM), 256, 0, stream>>>(
      minibatch, xT, T_DIM, (size_t)H_DIM * T_DIM, H_DIM, (size_t)T_DIM * H_DIM);

  // 3) m = xT @ emb_w^T + emb_b  (bf16)  -- 128 blocks, 1 round
  gemm8_kernel<1, true, 0><<<dim3(D_DIM / 256, BT / 256, 1), 512, 0, stream>>>(
      xT, wbf_emb, emb_b, nullptr, m_bf, nullptr, D_DIM, H_DIM, H_DIM, H_DIM, 0, 0, 0);

  // 4) KQV = m @ [Wk;Wq;Wv]^T + b  (bf16, [8192][3072]) -- 384 blocks
  gemm8_kernel<1, true, 0><<<dim3(3072 / 256, BT / 256, 1), 512, 0, stream>>>(
      m_bf, wbf_kqv, kqv_b, nullptr, KQV, nullptr, 3072, D_DIM, D_DIM, D_DIM, 0, 0, 0);

  // 5) VT[b][d][t] = V[b][t][d]  (V = KQV cols 2048..3071)
  transpose_kernel<unsigned short><<<dim3(D_DIM / 32, T_DIM / 32, B_DIM), 256, 0, stream>>>(
      KQV + 2048, VT_bf, 3072, (size_t)T_DIM * 3072, T_DIM, (size_t)D_DIM * T_DIM);

  // 6) logitsT[b][s][t] = K[b,s]·Q[b,t]  (causal block skip: bn<bm)
  gemm8_kernel<2, false, 1><<<dim3(T_DIM / 256, T_DIM / 256, B_DIM), 512, 0, stream>>>(
      KQV, KQV + 1024, nullptr, logitsT, nullptr, nullptr, T_DIM, D_DIM, 3072, 3072,
      (size_t)T_DIM * 3072, (size_t)T_DIM * 3072, TT);

  // 7) column-softmax stats (per (b,s): max/sum over t >= s), fold 1/sqrt(D)
  softmax_stats_kernel<<<BT, 256, 0, stream>>>(logitsT, smax, sinv);

  // 8) probs[b][t][s] bf16, transposed
  probs_kernel<<<dim3(T_DIM / 32, T_DIM / 32, B_DIM), 256, 0, stream>>>(
      logitsT, smax, sinv, probs);

  // 9) fused PV + residual + output transpose: out[b][d][t] = sum_s probs*VT + m
  gemm8_kernel<4, false, 2><<<dim3(D_DIM / 256, T_DIM / 256, B_DIM), 512, 0, stream>>>(
      probs, VT_bf, nullptr, out, nullptr, m_bf, D_DIM, T_DIM, T_DIM, T_DIM,
      TT, (size_t)D_DIM * T_DIM, 0);
}

// Round 8
// 214.738 us; speedup vs baseline: 1.2348x; 1.2348x over previous
//
#include <hip/hip_runtime.h>

#define T_DIM 2048
#define D_DIM 1024
#define H_DIM 1024
#define B_DIM 4

typedef __attribute__((ext_vector_type(8))) __bf16 bf16x8;
typedef __attribute__((ext_vector_type(4))) float f32x4;
typedef __attribute__((ext_vector_type(8))) unsigned short us8;

__device__ __forceinline__ unsigned short f2b(float f) {
  union { float f; unsigned int u; } x; x.f = f;
  unsigned int r = x.u + 0x7fffu + ((x.u >> 16) & 1u);
  return (unsigned short)(r >> 16);
}
__device__ __forceinline__ float b2f(unsigned short b) {
  union { unsigned int u; float f; } x; x.u = ((unsigned int)b) << 16;
  return x.f;
}

__device__ __forceinline__ void async16(unsigned short* l, const unsigned short* g) {
  __builtin_amdgcn_global_load_lds((const __attribute__((address_space(1))) void*)g,
                                   (__attribute__((address_space(3))) void*)l,
                                   16, 0, 0);
}

// ---------------- fused weights prep: 4x f32->bf16 cvt + bias concat ----------------
__global__ __launch_bounds__(256) void prep_kernel(const float* __restrict__ ew,
                                                   const float* __restrict__ kw,
                                                   const float* __restrict__ qw,
                                                   const float* __restrict__ vw,
                                                   const float* __restrict__ kb,
                                                   const float* __restrict__ qb,
                                                   const float* __restrict__ vb,
                                                   unsigned short* __restrict__ oe,
                                                   unsigned short* __restrict__ okqv,
                                                   float* __restrict__ ob) {
  int bid = blockIdx.x;
  if (bid == 4096) {               // bias concat: 3072 floats = 768 float4
    #pragma unroll
    for (int k = 0; k < 3; k++) {
      int f4 = threadIdx.x + k * 256;
      int fi = f4 * 4;
      const float* src = fi < 1024 ? kb + fi : (fi < 2048 ? qb + (fi - 1024) : vb + (fi - 2048));
      *(float4*)(&ob[fi]) = *(const float4*)src;
    }
    return;
  }
  int i = bid * 256 + threadIdx.x;   // float4 index over 4 x 256K
  int seg = i >> 18;
  int off = i & 262143;
  const float* in = seg == 0 ? ew : (seg == 1 ? kw : (seg == 2 ? qw : vw));
  unsigned short* out = seg == 0 ? oe : okqv + (size_t)(seg - 1) * 1048576;
  float4 v = ((const float4*)in)[off];
  ushort4 o;
  o.x = f2b(v.x); o.y = f2b(v.y); o.z = f2b(v.z); o.w = f2b(v.w);
  ((ushort4*)out)[off] = o;
}

// ---------------- tiled transpose (+cvt to bf16) ----------------
template <typename TIN>
__global__ __launch_bounds__(256) void transpose_kernel(const TIN* __restrict__ in,
                                                        unsigned short* __restrict__ out,
                                                        int inLD, size_t sIn, int R, size_t sOut) {
  __shared__ TIN tile[32][33];
  int c0 = blockIdx.x * 32, r0 = blockIdx.y * 32;
  int tx = threadIdx.x & 31, ty = threadIdx.x >> 5;
  const TIN* I = in + (size_t)blockIdx.z * sIn;
  #pragma unroll
  for (int i = 0; i < 32; i += 8)
    tile[ty + i][tx] = I[(size_t)(r0 + ty + i) * inLD + (c0 + tx)];
  __syncthreads();
  unsigned short* O = out + (size_t)blockIdx.z * sOut;
  #pragma unroll
  for (int i = 0; i < 32; i += 8) {
    TIN v = tile[tx][ty + i];
    unsigned short bb;
    if constexpr (sizeof(TIN) == 4) bb = f2b((float)v);
    else bb = (unsigned short)v;
    O[(size_t)(c0 + ty + i) * R + (r0 + tx)] = bb;
  }
}

// ============ 128x256 B^T GEMM, triple-buffered, 1 barrier / K-tile ============
// 512 thr = 8 waves (2M x 4N), per-wave 64x64 (acc[4][4]), BK=64, 32 MFMA/K-tile/wave.
// LDS: 3 bufs x (A 128x64 + B 256x64) bf16 = 144 KiB, XOR-swizzled.
// Depth-2 prefetch ledger: prologue stages t0,t1 (12 loads), vmcnt(6) -> t0 resident.
//   Iter t: 16 ds_read_b128 from buf(t%3); stage ALL 6 units of t+2 into buf((t+2)%3)
//   (that buffer's reads lgkm-retired before the PREVIOUS barrier -> no write/read race);
//   32 MFMA (setprio-wrapped); vmcnt(6) -> t+1 resident; s_barrier. Tail: vmcnt(0).
// OMODE: 1 bf16 C (+opt bias); 2 f32 C; 4 PV-fused out[b][d][t] = acc + m_res (transposed).
// SKIP: 1 causal block skip (logits [s][t]); 2 causal K-limit (PV: nt=(bm+1)*2).

#define BAR_ asm volatile("s_barrier" ::: "memory")
#define VM6_ asm volatile("s_waitcnt vmcnt(6)" ::: "memory")
#define VM0_ asm volatile("s_waitcnt vmcnt(0)" ::: "memory")

#define STGA3(t, bb, u) async16(smem + (bb) * 24576 + (u) * 4096 + tid * 8, \
                                A + (size_t)((u) * 64 + rl0) * lda + (t) * 64 + ce)
#define STGB3(t, bb, u) async16(smem + (bb) * 24576 + 8192 + (u) * 4096 + tid * 8, \
                                Bm + (size_t)((u) * 64 + rl0) * ldb + (t) * 64 + ce)
#define STGTILE(t, bb) do { STGA3(t, bb, 0); STGA3(t, bb, 1); \
    STGB3(t, bb, 0); STGB3(t, bb, 1); STGB3(t, bb, 2); STGB3(t, bb, 3); } while (0)

#define FRG(base, row, ks) \
  (*(const bf16x8*)((base) + (row) * 64 + ((((ks) << 2) | hi) ^ (lo & 7)) * 8))

#define LOADFRAGS(bA, bB)                                            \
  _Pragma("unroll") for (int m_ = 0; m_ < 4; m_++) {                 \
    af[m_][0] = FRG(bA, wr * 64 + m_ * 16 + lo, 0);                  \
    af[m_][1] = FRG(bA, wr * 64 + m_ * 16 + lo, 1);                  \
  }                                                                  \
  _Pragma("unroll") for (int n_ = 0; n_ < 4; n_++) {                 \
    bg[n_][0] = FRG(bB, wc * 64 + n_ * 16 + lo, 0);                  \
    bg[n_][1] = FRG(bB, wc * 64 + n_ * 16 + lo, 1);                  \
  }

#define MFMA32_                                                          \
  __builtin_amdgcn_s_setprio(1);                                         \
  _Pragma("unroll") for (int ks_ = 0; ks_ < 2; ks_++)                    \
    _Pragma("unroll") for (int m_ = 0; m_ < 4; m_++)                     \
      _Pragma("unroll") for (int n_ = 0; n_ < 4; n_++)                   \
        acc[m_][n_] = __builtin_amdgcn_mfma_f32_16x16x32_bf16(           \
            af[m_][ks_], bg[n_][ks_], acc[m_][n_], 0, 0, 0);             \
  __builtin_amdgcn_s_setprio(0);

template <int OMODE, bool BIAS, int SKIP>
__global__ __launch_bounds__(512, 2)
void gemm8_kernel(const unsigned short* __restrict__ A,
                  const unsigned short* __restrict__ Bm,
                  const float* __restrict__ bias,
                  float* __restrict__ Cf, unsigned short* __restrict__ Cb,
                  const unsigned short* __restrict__ mres,
                  int N, int K, int lda, int ldb,
                  size_t sAb, size_t sBb, size_t sCb) {
  __shared__ __align__(16) unsigned short smem[73728];   // 3 x 48KB = 144 KiB

  // XCD-aware bijective swizzle (nwg % 8 == 0 for all our grids)
  int gx = gridDim.x;
  int nwg = gx * gridDim.y;
  int flat = blockIdx.x + gx * blockIdx.y;
  int cpx = nwg >> 3;
  int f2 = (flat & 7) * cpx + (flat >> 3);
  int bn = f2 % gx, bm = f2 / gx;
  int bz = blockIdx.z;
  if (SKIP == 1 && bn * 2 + 1 < bm) return;   // block's max t < min s -> all masked

  A  += (size_t)bz * sAb + (size_t)bm * 128 * lda;
  Bm += (size_t)bz * sBb + (size_t)bn * 256 * ldb;

  int tid = threadIdx.x;
  int lane = tid & 63, wid = tid >> 6;
  int wr = wid >> 2, wc = wid & 3;
  int lo = lane & 15, hi = lane >> 4;
  int rl0 = tid >> 3;
  int ce = 8 * ((tid & 7) ^ (rl0 & 7));   // pre-swizzled source chunk

  int nt = K / 64;
  if (SKIP == 2) nt = (bm + 1) * 2;       // kt = (bm+1)*128

  bf16x8 af[4][2], bg[4][2];
  f32x4 acc[4][4] = {};

  // prologue: tiles 0 and 1 fully staged; wait down to 6 -> tile0 resident
  STGTILE(0, 0);
  STGTILE(1, 1);
  VM6_; BAR_;

  int cur = 0;
  for (int t = 0; t < nt - 2; t++) {
    const unsigned short* bA = smem + cur * 24576;
    const unsigned short* bB = bA + 8192;
    LOADFRAGS(bA, bB)
    int b2 = cur + 2; if (b2 >= 3) b2 -= 3;
    STGTILE(t + 2, b2);
    MFMA32_
    VM6_; BAR_;
    cur = (cur + 1 == 3) ? 0 : cur + 1;
  }
  { // t = nt-2: no more staging; full drain so tile nt-1 is resident
    const unsigned short* bA = smem + cur * 24576;
    const unsigned short* bB = bA + 8192;
    LOADFRAGS(bA, bB)
    MFMA32_
    VM0_; BAR_;
    cur = (cur + 1 == 3) ? 0 : cur + 1;
  }
  { // t = nt-1: pure compute
    const unsigned short* bA = smem + cur * 24576;
    const unsigned short* bB = bA + 8192;
    LOADFRAGS(bA, bB)
    MFMA32_
  }

  // ---------------- epilogue: LDS retile -> coalesced 16B stores ----------------
  __syncthreads();
  int row0 = bm * 128, col0 = bn * 256;
  size_t coff = (size_t)bz * sCb;

  if (OMODE == 1) {
    unsigned short* ep = smem;   // [128][264] padded
    #pragma unroll
    for (int n = 0; n < 4; n++) {
      int cl = wc * 64 + n * 16 + lo;
      float bv = BIAS ? bias[col0 + cl] : 0.f;
      #pragma unroll
      for (int m = 0; m < 4; m++) {
        int rl = wr * 64 + m * 16 + hi * 4;
        #pragma unroll
        for (int j = 0; j < 4; j++)
          ep[(rl + j) * 264 + cl] = f2b(acc[m][n][j] + bv);
      }
    }
    __syncthreads();
    #pragma unroll
    for (int it = 0; it < 8; it++) {
      int idx = it * 512 + tid, r = idx >> 5, c = idx & 31;
      *(uint4*)(Cb + coff + (size_t)(row0 + r) * N + col0 + c * 8) =
          *(const uint4*)(ep + r * 264 + c * 8);
    }
  } else if (OMODE == 2) {
    float* ep = (float*)smem;    // [64][260] padded
    #pragma unroll
    for (int half = 0; half < 2; half++) {
      __syncthreads();
      if (wr == half) {
        #pragma unroll
        for (int n = 0; n < 4; n++) {
          int cl = wc * 64 + n * 16 + lo;
          #pragma unroll
          for (int m = 0; m < 4; m++) {
            int rl = m * 16 + hi * 4;
            #pragma unroll
            for (int j = 0; j < 4; j++) ep[(rl + j) * 260 + cl] = acc[m][n][j];
          }
        }
      }
      __syncthreads();
      #pragma unroll
      for (int it = 0; it < 8; it++) {
        int idx = it * 512 + tid, r = idx >> 6, c = idx & 63;
        *(float4*)(Cf + coff + (size_t)(row0 + half * 64 + r) * N + col0 + c * 4) =
            *(const float4*)(ep + r * 260 + c * 4);
      }
    }
  } else {   // OMODE == 4: out[b][d][t] = acc + m[b][t][d], transposed coalesced write
    float* ep = (float*)smem;    // [128 d][132 t] padded
    #pragma unroll
    for (int half = 0; half < 2; half++) {
      __syncthreads();
      if ((wc >> 1) == half) {
        #pragma unroll
        for (int n = 0; n < 4; n++) {
          int cl = wc * 64 + n * 16 + lo;
          #pragma unroll
          for (int m = 0; m < 4; m++) {
            int rl = wr * 64 + m * 16 + hi * 4;
            #pragma unroll
            for (int j = 0; j < 4; j++) {
              float v = acc[m][n][j] +
                        b2f(mres[((size_t)bz * T_DIM + row0 + rl + j) * D_DIM + col0 + cl]);
              ep[(cl & 127) * 132 + rl + j] = v;
            }
          }
        }
      }
      __syncthreads();
      #pragma unroll
      for (int it = 0; it < 8; it++) {
        int idx = it * 512 + tid, r = idx >> 5, c = idx & 31;
        *(float4*)(Cf + ((size_t)bz * D_DIM + col0 + half * 128 + r) * T_DIM + row0 + c * 4) =
            *(const float4*)(ep + r * 132 + c * 4);
      }
    }
  }
}

// ---------------- softmax stats over rows of bf16 logitsT (= axis-1 of logits) ----------------
__device__ __forceinline__ float wred_max(float v) {
  #pragma unroll
  for (int o = 32; o > 0; o >>= 1) v = fmaxf(v, __shfl_down(v, o, 64));
  return v;
}
__device__ __forceinline__ float wred_sum(float v) {
  #pragma unroll
  for (int o = 32; o > 0; o >>= 1) v += __shfl_down(v, o, 64);
  return v;
}

// One row = 2048 bf16 = 256 threads x us8: single vector load, max+sum from registers.
__global__ __launch_bounds__(256) void softmax_stats_kernel(const unsigned short* __restrict__ lg,
                                                            float* __restrict__ smax,
                                                            float* __restrict__ sinv) {
  __shared__ float sb[4];
  int row = blockIdx.x;            // b*T + s
  int s = row & (T_DIM - 1);
  us8 v = ((const us8*)(lg + (size_t)row * T_DIM))[threadIdx.x];
  int tb = threadIdx.x * 8;
  float x[8];
  float mx = -3.4e38f;
  #pragma unroll
  for (int j = 0; j < 8; j++) {
    x[j] = (tb + j >= s) ? b2f(v[j]) : -3.4e38f;   // masked lanes -> -inf-ish
    mx = fmaxf(mx, x[j]);
  }
  mx = wred_max(mx);
  if ((threadIdx.x & 63) == 0) sb[threadIdx.x >> 6] = mx;
  __syncthreads();
  mx = fmaxf(fmaxf(sb[0], sb[1]), fmaxf(sb[2], sb[3]));
  __syncthreads();
  float sum = 0.f;
  #pragma unroll
  for (int j = 0; j < 8; j++) sum += __expf(x[j] - mx);   // masked: exp(-huge) = 0
  sum = wred_sum(sum);
  if ((threadIdx.x & 63) == 0) sb[threadIdx.x >> 6] = sum;
  __syncthreads();
  if (threadIdx.x == 0) {
    float tot = sb[0] + sb[1] + sb[2] + sb[3];
    smax[row] = mx;
    sinv[row] = 1.0f / (tot * 32.0f);   // fold 1/sqrt(D)=1/32 into the normalizer
  }
}

// ---------------- normalize + transpose: probs[t][s] bf16 from bf16 logitsT[s][t] ----------------
__global__ __launch_bounds__(256) void probs_kernel(const unsigned short* __restrict__ lg,
                                                    const float* __restrict__ smax,
                                                    const float* __restrict__ sinv,
                                                    unsigned short* __restrict__ probs) {
  int bz = blockIdx.z;
  int t0 = blockIdx.x * 32, s0 = blockIdx.y * 32;
  if (s0 >= (((t0 >> 7) + 1) << 7)) return;   // never read by the K-limited PV GEMM (128-tiles)
  __shared__ unsigned short tile[32][33];
  int tx = threadIdx.x & 31, ty = threadIdx.x >> 5;
  const unsigned short* L = lg + (size_t)bz * T_DIM * T_DIM;
  #pragma unroll
  for (int i = 0; i < 32; i += 8)
    tile[ty + i][tx] = L[(size_t)(s0 + ty + i) * T_DIM + (t0 + tx)];
  __syncthreads();
  unsigned short* P = probs + (size_t)bz * T_DIM * T_DIM;
  #pragma unroll
  for (int i = 0; i < 32; i += 8) {
    int t = t0 + ty + i, s = s0 + tx;
    float x = b2f(tile[tx][ty + i]);
    float p = (t >= s) ? __expf(x - smax[bz * T_DIM + s]) * sinv[bz * T_DIM + s] : 0.f;
    P[(size_t)t * T_DIM + s] = f2b(p);
  }
}

extern "C" void kernel_launch(void* const* d_in, const int* in_sizes, int n_in,
                              void* d_out, int out_size, void* d_ws, size_t ws_size,
                              hipStream_t stream) {
  const float* minibatch = (const float*)d_in[0];
  const float* emb_w   = (const float*)d_in[1];
  const float* emb_b   = (const float*)d_in[2];
  const float* key_w   = (const float*)d_in[3];
  const float* key_b   = (const float*)d_in[4];
  const float* query_w = (const float*)d_in[5];
  const float* query_b = (const float*)d_in[6];
  const float* value_w = (const float*)d_in[7];
  const float* value_b = (const float*)d_in[8];
  float* out = (float*)d_out;

  char* ws = (char*)d_ws;
  const size_t MB = 1ull << 20;
  unsigned short* wbf_emb = (unsigned short*)(ws + 0 * MB);    // 2 MB
  unsigned short* wbf_kqv = (unsigned short*)(ws + 2 * MB);    // 6 MB [key|query|value]
  float*          kqv_b   = (float*)(ws + 8 * MB);             // 12 KB
  unsigned short* m_bf    = (unsigned short*)(ws + 9 * MB);    // 16 MB, live to end
  unsigned short* KQV     = (unsigned short*)(ws + 25 * MB);   // 48 MB (dead after logits)
  unsigned short* VT_bf   = (unsigned short*)(ws + 73 * MB);   // 16 MB
  unsigned short* logits_bf = (unsigned short*)(ws + 89 * MB); // 32 MB (bf16 logitsT)
  unsigned short* xT      = (unsigned short*)(ws + 153 * MB);  // 16 MB (dead after emb GEMM)
  unsigned short* probs   = (unsigned short*)(ws + 153 * MB);  // 32 MB, aliases xT
  float*          smax    = (float*)(ws + 186 * MB);
  float*          sinv    = (float*)(ws + 186 * MB + 32768);

  const int BT = B_DIM * T_DIM;   // 8192
  const size_t TT = (size_t)T_DIM * T_DIM;

  // 1) weights -> bf16 + bias concat (single launch)
  prep_kernel<<<4097, 256, 0, stream>>>(emb_w, key_w, query_w, value_w,
                                        key_b, query_b, value_b,
                                        wbf_emb, wbf_kqv, kqv_b);

  // 2) xT[b][t][h] = minibatch[b][h][t], bf16
  transpose_kernel<float><<<dim3(T_DIM / 32, H_DIM / 32, B_DIM), 256, 0, stream>>>(
      minibatch, xT, T_DIM, (size_t)H_DIM * T_DIM, H_DIM, (size_t)T_DIM * H_DIM);

  // 3) m = xT @ emb_w^T + emb_b  (bf16)  -- 256 blocks, 1 round exact
  gemm8_kernel<1, true, 0><<<dim3(D_DIM / 256, BT / 128, 1), 512, 0, stream>>>(
      xT, wbf_emb, emb_b, nullptr, m_bf, nullptr, D_DIM, H_DIM, H_DIM, H_DIM, 0, 0, 0);

  // 4) KQV = m @ [Wk;Wq;Wv]^T + b  (bf16, [8192][3072]) -- 768 blocks = 3 exact rounds
  gemm8_kernel<1, true, 0><<<dim3(3072 / 256, BT / 128, 1), 512, 0, stream>>>(
      m_bf, wbf_kqv, kqv_b, nullptr, KQV, nullptr, 3072, D_DIM, D_DIM, D_DIM, 0, 0, 0);

  // 5) VT[b][d][t] = V[b][t][d]  (V = KQV cols 2048..3071)
  transpose_kernel<unsigned short><<<dim3(D_DIM / 32, T_DIM / 32, B_DIM), 256, 0, stream>>>(
      KQV + 2048, VT_bf, 3072, (size_t)T_DIM * 3072, T_DIM, (size_t)D_DIM * T_DIM);

  // 6) logitsT[b][s][t] = K[b,s]·Q[b,t]  (causal block skip; bf16 output)
  gemm8_kernel<1, false, 1><<<dim3(T_DIM / 256, T_DIM / 128, B_DIM), 512, 0, stream>>>(
      KQV, KQV + 1024, nullptr, nullptr, logits_bf, nullptr, T_DIM, D_DIM, 3072, 3072,
      (size_t)T_DIM * 3072, (size_t)T_DIM * 3072, TT);

  // 7) column-softmax stats (per (b,s): max/sum over t >= s), fold 1/sqrt(D)
  softmax_stats_kernel<<<BT, 256, 0, stream>>>(logits_bf, smax, sinv);

  // 8) probs[b][t][s] bf16, transposed
  probs_kernel<<<dim3(T_DIM / 32, T_DIM / 32, B_DIM), 256, 0, stream>>>(
      logits_bf, smax, sinv, probs);

  // 9) fused PV + residual + output transpose: out[b][d][t] = sum_s probs*VT + m
  gemm8_kernel<4, false, 2><<<dim3(D_DIM / 256, T_DIM / 128, B_DIM), 512, 0, stream>>>(
      probs, VT_bf, nullptr, out, nullptr, m_bf, D_DIM, T_DIM, T_DIM, T_DIM,
      TT, (size_t)D_DIM * T_DIM, 0);
}

// Round 9
// 210.696 us; speedup vs baseline: 1.2585x; 1.0192x over previous
//
#include <hip/hip_runtime.h>

#define T_DIM 2048
#define D_DIM 1024
#define H_DIM 1024
#define B_DIM 4

typedef __attribute__((ext_vector_type(8))) __bf16 bf16x8;
typedef __attribute__((ext_vector_type(4))) float f32x4;
typedef __attribute__((ext_vector_type(8))) unsigned short us8;

__device__ __forceinline__ unsigned short f2b(float f) {
  union { float f; unsigned int u; } x; x.f = f;
  unsigned int r = x.u + 0x7fffu + ((x.u >> 16) & 1u);
  return (unsigned short)(r >> 16);
}
__device__ __forceinline__ float b2f(unsigned short b) {
  union { unsigned int u; float f; } x; x.u = ((unsigned int)b) << 16;
  return x.f;
}

__device__ __forceinline__ void async16(unsigned short* l, const unsigned short* g) {
  __builtin_amdgcn_global_load_lds((const __attribute__((address_space(1))) void*)g,
                                   (__attribute__((address_space(3))) void*)l,
                                   16, 0, 0);
}

// ---------------- fused weights prep: 4x f32->bf16 cvt + bias concat ----------------
__global__ __launch_bounds__(256) void prep_kernel(const float* __restrict__ ew,
                                                   const float* __restrict__ kw,
                                                   const float* __restrict__ qw,
                                                   const float* __restrict__ vw,
                                                   const float* __restrict__ kb,
                                                   const float* __restrict__ qb,
                                                   const float* __restrict__ vb,
                                                   unsigned short* __restrict__ oe,
                                                   unsigned short* __restrict__ okqv,
                                                   float* __restrict__ ob) {
  int bid = blockIdx.x;
  if (bid == 4096) {               // bias concat: 3072 floats = 768 float4
    #pragma unroll
    for (int k = 0; k < 3; k++) {
      int f4 = threadIdx.x + k * 256;
      int fi = f4 * 4;
      const float* src = fi < 1024 ? kb + fi : (fi < 2048 ? qb + (fi - 1024) : vb + (fi - 2048));
      *(float4*)(&ob[fi]) = *(const float4*)src;
    }
    return;
  }
  int i = bid * 256 + threadIdx.x;   // float4 index over 4 x 256K
  int seg = i >> 18;
  int off = i & 262143;
  const float* in = seg == 0 ? ew : (seg == 1 ? kw : (seg == 2 ? qw : vw));
  unsigned short* out = seg == 0 ? oe : okqv + (size_t)(seg - 1) * 1048576;
  float4 v = ((const float4*)in)[off];
  ushort4 o;
  o.x = f2b(v.x); o.y = f2b(v.y); o.z = f2b(v.z); o.w = f2b(v.w);
  ((ushort4*)out)[off] = o;
}

// ---------------- tiled transpose (+cvt to bf16) ----------------
template <typename TIN>
__global__ __launch_bounds__(256) void transpose_kernel(const TIN* __restrict__ in,
                                                        unsigned short* __restrict__ out,
                                                        int inLD, size_t sIn, int R, size_t sOut) {
  __shared__ TIN tile[32][33];
  int c0 = blockIdx.x * 32, r0 = blockIdx.y * 32;
  int tx = threadIdx.x & 31, ty = threadIdx.x >> 5;
  const TIN* I = in + (size_t)blockIdx.z * sIn;
  #pragma unroll
  for (int i = 0; i < 32; i += 8)
    tile[ty + i][tx] = I[(size_t)(r0 + ty + i) * inLD + (c0 + tx)];
  __syncthreads();
  unsigned short* O = out + (size_t)blockIdx.z * sOut;
  #pragma unroll
  for (int i = 0; i < 32; i += 8) {
    TIN v = tile[tx][ty + i];
    unsigned short bb;
    if constexpr (sizeof(TIN) == 4) bb = f2b((float)v);
    else bb = (unsigned short)v;
    O[(size_t)(c0 + ty + i) * R + (r0 + tx)] = bb;
  }
}

// ============ 128x256 B^T GEMM, triple-buffered, 1 barrier / K-tile ============
// (unchanged from R8 -- measured 33% MfmaUtil, 0 bank conflicts)

#define BAR_ asm volatile("s_barrier" ::: "memory")
#define VM6_ asm volatile("s_waitcnt vmcnt(6)" ::: "memory")
#define VM4_ asm volatile("s_waitcnt vmcnt(4)" ::: "memory")
#define VM0_ asm volatile("s_waitcnt vmcnt(0)" ::: "memory")

#define STGA3(t, bb, u) async16(smem + (bb) * 24576 + (u) * 4096 + tid * 8, \
                                A + (size_t)((u) * 64 + rl0) * lda + (t) * 64 + ce)
#define STGB3(t, bb, u) async16(smem + (bb) * 24576 + 8192 + (u) * 4096 + tid * 8, \
                                Bm + (size_t)((u) * 64 + rl0) * ldb + (t) * 64 + ce)
#define STGTILE(t, bb) do { STGA3(t, bb, 0); STGA3(t, bb, 1); \
    STGB3(t, bb, 0); STGB3(t, bb, 1); STGB3(t, bb, 2); STGB3(t, bb, 3); } while (0)

#define FRG(base, row, ks) \
  (*(const bf16x8*)((base) + (row) * 64 + ((((ks) << 2) | hi) ^ (lo & 7)) * 8))

#define LOADFRAGS(bA, bB)                                            \
  _Pragma("unroll") for (int m_ = 0; m_ < 4; m_++) {                 \
    af[m_][0] = FRG(bA, wr * 64 + m_ * 16 + lo, 0);                  \
    af[m_][1] = FRG(bA, wr * 64 + m_ * 16 + lo, 1);                  \
  }                                                                  \
  _Pragma("unroll") for (int n_ = 0; n_ < 4; n_++) {                 \
    bg[n_][0] = FRG(bB, wc * 64 + n_ * 16 + lo, 0);                  \
    bg[n_][1] = FRG(bB, wc * 64 + n_ * 16 + lo, 1);                  \
  }

#define MFMA32_                                                          \
  __builtin_amdgcn_s_setprio(1);                                         \
  _Pragma("unroll") for (int ks_ = 0; ks_ < 2; ks_++)                    \
    _Pragma("unroll") for (int m_ = 0; m_ < 4; m_++)                     \
      _Pragma("unroll") for (int n_ = 0; n_ < 4; n_++)                   \
        acc[m_][n_] = __builtin_amdgcn_mfma_f32_16x16x32_bf16(           \
            af[m_][ks_], bg[n_][ks_], acc[m_][n_], 0, 0, 0);             \
  __builtin_amdgcn_s_setprio(0);

template <int OMODE, bool BIAS, int SKIP>
__global__ __launch_bounds__(512, 2)
void gemm8_kernel(const unsigned short* __restrict__ A,
                  const unsigned short* __restrict__ Bm,
                  const float* __restrict__ bias,
                  float* __restrict__ Cf, unsigned short* __restrict__ Cb,
                  int N, int K, int lda, int ldb,
                  size_t sAb, size_t sBb, size_t sCb) {
  __shared__ __align__(16) unsigned short smem[73728];   // 3 x 48KB = 144 KiB

  // XCD-aware bijective swizzle (nwg % 8 == 0 for all our grids)
  int gx = gridDim.x;
  int nwg = gx * gridDim.y;
  int flat = blockIdx.x + gx * blockIdx.y;
  int cpx = nwg >> 3;
  int f2 = (flat & 7) * cpx + (flat >> 3);
  int bn = f2 % gx, bm = f2 / gx;
  int bz = blockIdx.z;
  if (SKIP == 1 && bn * 2 + 1 < bm) return;   // block's max t < min s -> all masked

  A  += (size_t)bz * sAb + (size_t)bm * 128 * lda;
  Bm += (size_t)bz * sBb + (size_t)bn * 256 * ldb;

  int tid = threadIdx.x;
  int lane = tid & 63, wid = tid >> 6;
  int wr = wid >> 2, wc = wid & 3;
  int lo = lane & 15, hi = lane >> 4;
  int rl0 = tid >> 3;
  int ce = 8 * ((tid & 7) ^ (rl0 & 7));   // pre-swizzled source chunk

  int nt = K / 64;

  bf16x8 af[4][2], bg[4][2];
  f32x4 acc[4][4] = {};

  STGTILE(0, 0);
  STGTILE(1, 1);
  VM6_; BAR_;

  int cur = 0;
  for (int t = 0; t < nt - 2; t++) {
    const unsigned short* bA = smem + cur * 24576;
    const unsigned short* bB = bA + 8192;
    LOADFRAGS(bA, bB)
    int b2 = cur + 2; if (b2 >= 3) b2 -= 3;
    STGTILE(t + 2, b2);
    MFMA32_
    VM6_; BAR_;
    cur = (cur + 1 == 3) ? 0 : cur + 1;
  }
  {
    const unsigned short* bA = smem + cur * 24576;
    const unsigned short* bB = bA + 8192;
    LOADFRAGS(bA, bB)
    MFMA32_
    VM0_; BAR_;
    cur = (cur + 1 == 3) ? 0 : cur + 1;
  }
  {
    const unsigned short* bA = smem + cur * 24576;
    const unsigned short* bB = bA + 8192;
    LOADFRAGS(bA, bB)
    MFMA32_
  }

  // epilogue: LDS retile -> coalesced 16B stores
  __syncthreads();
  int row0 = bm * 128, col0 = bn * 256;
  size_t coff = (size_t)bz * sCb;

  if (OMODE == 1) {
    unsigned short* ep = smem;   // [128][264] padded
    #pragma unroll
    for (int n = 0; n < 4; n++) {
      int cl = wc * 64 + n * 16 + lo;
      float bv = BIAS ? bias[col0 + cl] : 0.f;
      #pragma unroll
      for (int m = 0; m < 4; m++) {
        int rl = wr * 64 + m * 16 + hi * 4;
        #pragma unroll
        for (int j = 0; j < 4; j++)
          ep[(rl + j) * 264 + cl] = f2b(acc[m][n][j] + bv);
      }
    }
    __syncthreads();
    #pragma unroll
    for (int it = 0; it < 8; it++) {
      int idx = it * 512 + tid, r = idx >> 5, c = idx & 31;
      *(uint4*)(Cb + coff + (size_t)(row0 + r) * N + col0 + c * 8) =
          *(const uint4*)(ep + r * 264 + c * 8);
    }
  } else {   // OMODE == 2: f32 out
    float* ep = (float*)smem;    // [64][260] padded
    #pragma unroll
    for (int half = 0; half < 2; half++) {
      __syncthreads();
      if (wr == half) {
        #pragma unroll
        for (int n = 0; n < 4; n++) {
          int cl = wc * 64 + n * 16 + lo;
          #pragma unroll
          for (int m = 0; m < 4; m++) {
            int rl = m * 16 + hi * 4;
            #pragma unroll
            for (int j = 0; j < 4; j++) ep[(rl + j) * 260 + cl] = acc[m][n][j];
          }
        }
      }
      __syncthreads();
      #pragma unroll
      for (int it = 0; it < 8; it++) {
        int idx = it * 512 + tid, r = idx >> 6, c = idx & 63;
        *(float4*)(Cf + coff + (size_t)(row0 + half * 64 + r) * N + col0 + c * 4) =
            *(const float4*)(ep + r * 260 + c * 4);
      }
    }
  }
}

// ============ Paired causal PV: uniform-work blocks ============
// Block (bn, jj, bz): d-tile bn (128 wide), t-tiles jj (K=(jj+1)*128) AND 15-jj
// (K=(16-jj)*128) -> every block does K-sum 17*128 = 2176 (perfect balance).
// 512 thr = 8 waves 2(t) x 4(d); per-wave 64(t) x 32(d), acc[4][2].
// LDS: 3 bufs x (A 128x64 + B 128x64) = 96 KiB, same swizzle/ledger as gemm8
// (prologue 2 tiles, vmcnt(4) counted, stage t+2 into dead buffer).
// Epilogue: out[b][d][t] = acc + m[b][t][d], LDS retile -> coalesced float4.

#define PSTGA(t, bb, u) async16(smem + (bb) * 16384 + (u) * 4096 + tid * 8, \
                                Ap + (size_t)((u) * 64 + rl0) * T_DIM + (t) * 64 + ce)
#define PSTGB(t, bb, u) async16(smem + (bb) * 16384 + 8192 + (u) * 4096 + tid * 8, \
                                Bp + (size_t)((u) * 64 + rl0) * T_DIM + (t) * 64 + ce)
#define PSTG(t, bb) do { PSTGA(t, bb, 0); PSTGA(t, bb, 1); \
                         PSTGB(t, bb, 0); PSTGB(t, bb, 1); } while (0)

#define PVFRAGS(bA, bB)                                              \
  _Pragma("unroll") for (int m_ = 0; m_ < 4; m_++) {                 \
    af[m_][0] = FRG(bA, wr * 64 + m_ * 16 + lo, 0);                  \
    af[m_][1] = FRG(bA, wr * 64 + m_ * 16 + lo, 1);                  \
  }                                                                  \
  _Pragma("unroll") for (int n_ = 0; n_ < 2; n_++) {                 \
    bg[n_][0] = FRG(bB, wc * 32 + n_ * 16 + lo, 0);                  \
    bg[n_][1] = FRG(bB, wc * 32 + n_ * 16 + lo, 1);                  \
  }

#define PVMFMA_                                                          \
  __builtin_amdgcn_s_setprio(1);                                         \
  _Pragma("unroll") for (int ks_ = 0; ks_ < 2; ks_++)                    \
    _Pragma("unroll") for (int m_ = 0; m_ < 4; m_++)                     \
      _Pragma("unroll") for (int n_ = 0; n_ < 2; n_++)                   \
        acc[m_][n_] = __builtin_amdgcn_mfma_f32_16x16x32_bf16(           \
            af[m_][ks_], bg[n_][ks_], acc[m_][n_], 0, 0, 0);             \
  __builtin_amdgcn_s_setprio(0);

__global__ __launch_bounds__(512, 2)
void pv_kernel(const unsigned short* __restrict__ probs,
               const unsigned short* __restrict__ VT,
               const unsigned short* __restrict__ mres,
               float* __restrict__ out) {
  __shared__ __align__(16) unsigned short smem[49152];   // 96 KiB
  int bn = blockIdx.x;        // d-tile (128 wide), 0..7
  int jj = blockIdx.y;        // pair id 0..7
  int bz = blockIdx.z;
  int tid = threadIdx.x;
  int lane = tid & 63, wid = tid >> 6;
  int wr = wid >> 2, wc = wid & 3;      // wr 0..1 (t-half), wc 0..3 (d-quarter)
  int lo = lane & 15, hi = lane >> 4;
  int rl0 = tid >> 3;
  int ce = 8 * ((tid & 7) ^ (rl0 & 7));

  const unsigned short* Bp = VT + (size_t)bz * D_DIM * T_DIM + (size_t)(bn * 128) * T_DIM;

  #pragma unroll 1
  for (int seg = 0; seg < 2; seg++) {
    int jt = (seg == 0) ? jj : (15 - jj);
    int nt = ((seg == 0) ? (jj + 1) : (16 - jj)) * 2;
    const unsigned short* Ap = probs + (size_t)bz * T_DIM * T_DIM + (size_t)(jt * 128) * T_DIM;

    bf16x8 af[4][2], bg[2][2];
    f32x4 acc[4][2] = {};

    PSTG(0, 0);
    PSTG(1, 1);
    VM4_; BAR_;

    int cur = 0;
    for (int t = 0; t < nt - 2; t++) {
      const unsigned short* bA = smem + cur * 16384;
      const unsigned short* bB = bA + 8192;
      PVFRAGS(bA, bB)
      int b2 = cur + 2; if (b2 >= 3) b2 -= 3;
      PSTG(t + 2, b2);
      PVMFMA_
      VM4_; BAR_;
      cur = (cur + 1 == 3) ? 0 : cur + 1;
    }
    {
      const unsigned short* bA = smem + cur * 16384;
      const unsigned short* bB = bA + 8192;
      PVFRAGS(bA, bB)
      PVMFMA_
      VM0_; BAR_;
      cur = (cur + 1 == 3) ? 0 : cur + 1;
    }
    {
      const unsigned short* bA = smem + cur * 16384;
      const unsigned short* bB = bA + 8192;
      PVFRAGS(bA, bB)
      PVMFMA_
    }

    // epilogue: ep[128 d][132 t] f32; out[b][d][t] = acc + m[b][t][d]
    __syncthreads();
    float* ep = (float*)smem;
    #pragma unroll
    for (int n = 0; n < 2; n++) {
      int dl = wc * 32 + n * 16 + lo;
      #pragma unroll
      for (int m = 0; m < 4; m++) {
        int tl = wr * 64 + m * 16 + hi * 4;
        #pragma unroll
        for (int j = 0; j < 4; j++) {
          float v = acc[m][n][j] +
              b2f(mres[((size_t)bz * T_DIM + jt * 128 + tl + j) * D_DIM + bn * 128 + dl]);
          ep[dl * 132 + tl + j] = v;
        }
      }
    }
    __syncthreads();
    #pragma unroll
    for (int it = 0; it < 8; it++) {
      int idx = it * 512 + tid, r = idx >> 5, c = idx & 31;
      *(float4*)(out + ((size_t)bz * D_DIM + bn * 128 + r) * T_DIM + jt * 128 + c * 4) =
          *(const float4*)(ep + r * 132 + c * 4);
    }
    __syncthreads();   // ep dead before next seg's staging
  }
}

// ---------------- softmax stats over rows of bf16 logitsT (= axis-1 of logits) ----------------
__device__ __forceinline__ float wred_max(float v) {
  #pragma unroll
  for (int o = 32; o > 0; o >>= 1) v = fmaxf(v, __shfl_down(v, o, 64));
  return v;
}
__device__ __forceinline__ float wred_sum(float v) {
  #pragma unroll
  for (int o = 32; o > 0; o >>= 1) v += __shfl_down(v, o, 64);
  return v;
}

__global__ __launch_bounds__(256) void softmax_stats_kernel(const unsigned short* __restrict__ lg,
                                                            float* __restrict__ smax,
                                                            float* __restrict__ sinv) {
  __shared__ float sb[4];
  int row = blockIdx.x;            // b*T + s
  int s = row & (T_DIM - 1);
  us8 v = ((const us8*)(lg + (size_t)row * T_DIM))[threadIdx.x];
  int tb = threadIdx.x * 8;
  float x[8];
  float mx = -3.4e38f;
  #pragma unroll
  for (int j = 0; j < 8; j++) {
    x[j] = (tb + j >= s) ? b2f(v[j]) : -3.4e38f;
    mx = fmaxf(mx, x[j]);
  }
  mx = wred_max(mx);
  if ((threadIdx.x & 63) == 0) sb[threadIdx.x >> 6] = mx;
  __syncthreads();
  mx = fmaxf(fmaxf(sb[0], sb[1]), fmaxf(sb[2], sb[3]));
  __syncthreads();
  float sum = 0.f;
  #pragma unroll
  for (int j = 0; j < 8; j++) sum += __expf(x[j] - mx);
  sum = wred_sum(sum);
  if ((threadIdx.x & 63) == 0) sb[threadIdx.x >> 6] = sum;
  __syncthreads();
  if (threadIdx.x == 0) {
    float tot = sb[0] + sb[1] + sb[2] + sb[3];
    smax[row] = mx;
    sinv[row] = 1.0f / (tot * 32.0f);   // fold 1/sqrt(D)=1/32
  }
}

// ---------------- normalize + transpose: probs[t][s] bf16 from bf16 logitsT[s][t] ----------------
__global__ __launch_bounds__(256) void probs_kernel(const unsigned short* __restrict__ lg,
                                                    const float* __restrict__ smax,
                                                    const float* __restrict__ sinv,
                                                    unsigned short* __restrict__ probs) {
  int bz = blockIdx.z;
  int t0 = blockIdx.x * 32, s0 = blockIdx.y * 32;
  if (s0 >= (((t0 >> 7) + 1) << 7)) return;   // never read by the K-limited PV (128-tiles)
  __shared__ unsigned short tile[32][33];
  int tx = threadIdx.x & 31, ty = threadIdx.x >> 5;
  const unsigned short* L = lg + (size_t)bz * T_DIM * T_DIM;
  #pragma unroll
  for (int i = 0; i < 32; i += 8)
    tile[ty + i][tx] = L[(size_t)(s0 + ty + i) * T_DIM + (t0 + tx)];
  __syncthreads();
  unsigned short* P = probs + (size_t)bz * T_DIM * T_DIM;
  #pragma unroll
  for (int i = 0; i < 32; i += 8) {
    int t = t0 + ty + i, s = s0 + tx;
    float x = b2f(tile[tx][ty + i]);
    float p = (t >= s) ? __expf(x - smax[bz * T_DIM + s]) * sinv[bz * T_DIM + s] : 0.f;
    P[(size_t)t * T_DIM + s] = f2b(p);
  }
}

extern "C" void kernel_launch(void* const* d_in, const int* in_sizes, int n_in,
                              void* d_out, int out_size, void* d_ws, size_t ws_size,
                              hipStream_t stream) {
  const float* minibatch = (const float*)d_in[0];
  const float* emb_w   = (const float*)d_in[1];
  const float* emb_b   = (const float*)d_in[2];
  const float* key_w   = (const float*)d_in[3];
  const float* key_b   = (const float*)d_in[4];
  const float* query_w = (const float*)d_in[5];
  const float* query_b = (const float*)d_in[6];
  const float* value_w = (const float*)d_in[7];
  const float* value_b = (const float*)d_in[8];
  float* out = (float*)d_out;

  char* ws = (char*)d_ws;
  const size_t MB = 1ull << 20;
  unsigned short* wbf_emb = (unsigned short*)(ws + 0 * MB);    // 2 MB
  unsigned short* wbf_kqv = (unsigned short*)(ws + 2 * MB);    // 6 MB [key|query|value]
  float*          kqv_b   = (float*)(ws + 8 * MB);             // 12 KB
  unsigned short* m_bf    = (unsigned short*)(ws + 9 * MB);    // 16 MB, live to end
  unsigned short* KQV     = (unsigned short*)(ws + 25 * MB);   // 48 MB (dead after logits)
  unsigned short* VT_bf   = (unsigned short*)(ws + 73 * MB);   // 16 MB
  unsigned short* logits_bf = (unsigned short*)(ws + 89 * MB); // 32 MB (bf16 logitsT)
  unsigned short* xT      = (unsigned short*)(ws + 153 * MB);  // 16 MB (dead after emb GEMM)
  unsigned short* probs   = (unsigned short*)(ws + 153 * MB);  // 32 MB, aliases xT
  float*          smax    = (float*)(ws + 186 * MB);
  float*          sinv    = (float*)(ws + 186 * MB + 32768);

  const int BT = B_DIM * T_DIM;   // 8192
  const size_t TT = (size_t)T_DIM * T_DIM;

  // 1) weights -> bf16 + bias concat
  prep_kernel<<<4097, 256, 0, stream>>>(emb_w, key_w, query_w, value_w,
                                        key_b, query_b, value_b,
                                        wbf_emb, wbf_kqv, kqv_b);

  // 2) xT[b][t][h] = minibatch[b][h][t], bf16
  transpose_kernel<float><<<dim3(T_DIM / 32, H_DIM / 32, B_DIM), 256, 0, stream>>>(
      minibatch, xT, T_DIM, (size_t)H_DIM * T_DIM, H_DIM, (size_t)T_DIM * H_DIM);

  // 3) m = xT @ emb_w^T + emb_b  (bf16) -- 256 blocks, 1 exact round
  gemm8_kernel<1, true, 0><<<dim3(D_DIM / 256, BT / 128, 1), 512, 0, stream>>>(
      xT, wbf_emb, emb_b, nullptr, m_bf, D_DIM, H_DIM, H_DIM, H_DIM, 0, 0, 0);

  // 4) KQV = m @ [Wk;Wq;Wv]^T + b  -- 768 blocks = 3 exact rounds
  gemm8_kernel<1, true, 0><<<dim3(3072 / 256, BT / 128, 1), 512, 0, stream>>>(
      m_bf, wbf_kqv, kqv_b, nullptr, KQV, 3072, D_DIM, D_DIM, D_DIM, 0, 0, 0);

  // 5) VT[b][d][t] = V[b][t][d]
  transpose_kernel<unsigned short><<<dim3(D_DIM / 32, T_DIM / 32, B_DIM), 256, 0, stream>>>(
      KQV + 2048, VT_bf, 3072, (size_t)T_DIM * 3072, T_DIM, (size_t)D_DIM * T_DIM);

  // 6) logitsT[b][s][t] = K[b,s]·Q[b,t]  (causal block skip; bf16 out)
  gemm8_kernel<1, false, 1><<<dim3(T_DIM / 256, T_DIM / 128, B_DIM), 512, 0, stream>>>(
      KQV, KQV + 1024, nullptr, nullptr, logits_bf, T_DIM, D_DIM, 3072, 3072,
      (size_t)T_DIM * 3072, (size_t)T_DIM * 3072, TT);

  // 7) column-softmax stats
  softmax_stats_kernel<<<BT, 256, 0, stream>>>(logits_bf, smax, sinv);

  // 8) probs[b][t][s] bf16, transposed
  probs_kernel<<<dim3(T_DIM / 32, T_DIM / 32, B_DIM), 256, 0, stream>>>(
      logits_bf, smax, sinv, probs);

  // 9) paired PV + residual + output transpose (256 uniform blocks)
  pv_kernel<<<dim3(8, 8, B_DIM), 512, 0, stream>>>(probs, VT_bf, m_bf, out);
}